// Round 5
// baseline (383.234 us; speedup 1.0000x reference)
//
#include <hip/hip_runtime.h>

// Swin window attention, R5: transposed-MFMA orientation so every D-fragment
// store is packed (lane's 4 values contiguous in the minor dim).
//   - QKV q/k: D=(W^T)(X^T)=[ch][tok] -> ushort4 LDS stores (was 4x b16)
//   - scores:  S^T = K.Q^T -> softmax per-lane column, 2 shuffle rounds
//              (was 8), no max-subtract (|S|<~0.5), float4 bias, packed P^T
//   - PV:      O^T = (V^T)(P^T) -> ushort4 direct-to-global oa[tok][ch];
//              phase5 + barrier + rsum deleted (1/sum folded into P)
//   - proj:    (Wout^T)(oa^T), B-frags straight from global (L1-resident
//              16KB/window) -> NO LDS, NO barrier, float4 out stores
//   - all f32->bf16 via (__bf16) casts -> v_cvt_pk_bf16_f32
// R4 counters driving this: VALUBusy 39% (top pipe), MfmaUtil 10.5%,
// Occ 31%, 5.5M LDS-conflict cycles -> VALU-issue + latency bound.
//
// MFMA 16x16x32 bf16 fragment layouts (HW-verified per guide m89/m91/m120):
//   A[m][k]: m = lane&15, k = (lane>>4)*8 + j   (8 contiguous bf16 = 16B)
//   B[k][n]: n = lane&15, k = (lane>>4)*8 + j
//   D[m][n]: n = lane&15, m = (lane>>4)*4 + reg

typedef __bf16 bf16x8 __attribute__((ext_vector_type(8)));
typedef __bf16 bf16x4 __attribute__((ext_vector_type(4)));
typedef short  s16x8  __attribute__((ext_vector_type(8)));
typedef short  s16x4  __attribute__((ext_vector_type(4)));
typedef float  f32x4  __attribute__((ext_vector_type(4)));

static __device__ __forceinline__ f32x4 mfma16(s16x8 a, s16x8 b, f32x4 c) {
  return __builtin_amdgcn_mfma_f32_16x16x32_bf16(
      __builtin_bit_cast(bf16x8, a), __builtin_bit_cast(bf16x8, b), c, 0, 0, 0);
}
static __device__ __forceinline__ s16x4 pack4(float a, float b, float c, float d) {
  bf16x4 v; v.x = (__bf16)a; v.y = (__bf16)b; v.z = (__bf16)c; v.w = (__bf16)d;
  return __builtin_bit_cast(s16x4, v);
}
static __device__ __forceinline__ unsigned short u16bf(float f) {
  return __builtin_bit_cast(unsigned short, (__bf16)f);
}

// ---------------- prep: weights (bf16, transposed) + bias variants ----------
__global__ void prep(const float* __restrict__ wqkv,
                     const float* __restrict__ wout,
                     const float* __restrict__ pe,
                     const float* __restrict__ ulm,
                     const float* __restrict__ lrm,
                     unsigned short* __restrict__ wqkvT,
                     unsigned short* __restrict__ woutT,
                     float* __restrict__ bias_g) {
  int idx = blockIdx.x * 256 + threadIdx.x;
  if (idx < 49152) {
    int n = idx >> 7, k = idx & 127;
    wqkvT[idx] = u16bf(wqkv[k * 384 + n]);
  } else if (idx < 65536) {
    int i2 = idx - 49152;
    int n = i2 >> 7, k = i2 & 127;
    woutT[i2] = u16bf(wout[k * 128 + n]);
  } else {
    int i3 = idx - 65536;                  // < 16384
    int var = i3 >> 12, t = i3 & 4095;
    int i = t >> 6, j = t & 63;
    int r0 = (j >> 3) - (i >> 3) + 7;
    int r1 = (j & 7) - (i & 7) + 7;
    float v = pe[r0 * 15 + r1];
    if (var & 2) v += ulm[t];
    if (var & 1) v += lrm[t];
    bias_g[i3] = v;
  }
}

// ---------------- K1: QKV + attention per (window, head-pair) ---------------
// LDS map (bytes):
//   xs [64][136] bf16 (17408) / Pt [2][64][72] bf16 (18432)  @ 0   (union)
//   q  [64tok][72ch] bf16  9216                              @ 18432
//   k  [64tok][72ch] bf16  9216                              @ 27648
//   v  [64ch][72tok] bf16  9216                              @ 36864
//   total 46080 -> 3 blocks/CU.
#define K1_OFF_XP  0
#define K1_OFF_Q   18432
#define K1_OFF_K   27648
#define K1_OFF_V   36864
#define K1_SMEM    46080

__global__ __launch_bounds__(256, 3)
void swin_attn(const float* __restrict__ x,
               const unsigned short* __restrict__ wqkvT,
               const float* __restrict__ bias_g,
               unsigned short* __restrict__ oa_ws) {
  __shared__ __align__(16) unsigned char smem[K1_SMEM];
  unsigned short* xs_s = (unsigned short*)(smem + K1_OFF_XP);
  unsigned short* Pt_s = (unsigned short*)(smem + K1_OFF_XP);   // union
  unsigned short* q_s  = (unsigned short*)(smem + K1_OFF_Q);
  unsigned short* k_s  = (unsigned short*)(smem + K1_OFF_K);
  unsigned short* v_s  = (unsigned short*)(smem + K1_OFF_V);

  const int tid  = threadIdx.x;
  const int lane = tid & 63;
  const int wave = tid >> 6;       // 0..3
  const int ln15 = lane & 15;
  const int quad = lane >> 4;

  const int bid = blockIdx.x;            // b*512 + win*2 + hp
  const int b   = bid >> 9;
  const int rem = bid & 511;
  const int win = rem >> 1;
  const int hp  = rem & 1;               // head pair: heads {2hp, 2hp+1}
  const int wh  = win >> 4, ww = win & 15;

  // ---- phase 0: stage rolled x window to LDS (bf16) ----
  {
    const int row0 = wh * 8, col0 = ww * 8;
#pragma unroll
    for (int it = 0; it < 8; ++it) {
      int t = tid + it * 256;              // 2048 float4 chunks
      int tok = t >> 5, c4 = t & 31;
      int ti = tok >> 3, tj = tok & 7;
      int gi = (row0 + ti + 4) & 127;
      int gj = (col0 + tj + 4) & 127;
      float4 v4 = *(const float4*)(x + (((b * 128 + gi) * 128 + gj) * 128 + c4 * 4));
      *(s16x4*)(xs_s + tok * 136 + c4 * 4) = pack4(v4.x, v4.y, v4.z, v4.w);
    }
  }
  __syncthreads();

  // ---- phase 1: QKV GEMM. 12 units (16 out-ch x 64 tok) over 4 waves ------
  // q/k: D = (W^T)(X^T) = [ch][tok]; store ushort4 of 4 consecutive ch.
  // v:   D = (X)(W)     = [tok][ch]; store ushort4 of 4 consecutive tok
  //      into v_s[ch][tok] (transposed layout for PV's A-operand).
  {
#pragma unroll
    for (int i = 0; i < 3; ++i) {
      int u   = wave + 4 * i;
      int sel = u >> 2;                   // 0=q 1=k 2=v (wave-uniform)
      int t   = u & 3;
      if (sel < 2) {
        const unsigned short* wp =
            wqkvT + (sel * 128 + hp * 64 + t * 16 + ln15) * 128 + quad * 8;
        s16x8 af[4];
#pragma unroll
        for (int ks = 0; ks < 4; ++ks) af[ks] = *(const s16x8*)(wp + ks * 32);
        unsigned short* dst = (sel == 0) ? q_s : k_s;
#pragma unroll
        for (int nt = 0; nt < 4; ++nt) {
          f32x4 acc = {0.f, 0.f, 0.f, 0.f};
#pragma unroll
          for (int ks = 0; ks < 4; ++ks) {
            s16x8 bf = *(const s16x8*)(xs_s + (nt * 16 + ln15) * 136 + ks * 32 + quad * 8);
            acc = mfma16(af[ks], bf, acc);
          }
          // D: n=ln15 -> tok, m=quad*4+r -> ch-in-tile
          *(s16x4*)(dst + (nt * 16 + ln15) * 72 + t * 16 + quad * 4) =
              pack4(acc[0], acc[1], acc[2], acc[3]);
        }
      } else {
        const unsigned short* wp =
            wqkvT + (256 + hp * 64 + t * 16 + ln15) * 128 + quad * 8;
        s16x8 bfr[4];
#pragma unroll
        for (int ks = 0; ks < 4; ++ks) bfr[ks] = *(const s16x8*)(wp + ks * 32);
#pragma unroll
        for (int mt = 0; mt < 4; ++mt) {
          f32x4 acc = {0.f, 0.f, 0.f, 0.f};
#pragma unroll
          for (int ks = 0; ks < 4; ++ks) {
            s16x8 af = *(const s16x8*)(xs_s + (mt * 16 + ln15) * 136 + ks * 32 + quad * 8);
            acc = mfma16(af, bfr[ks], acc);
          }
          // D: n=ln15 -> ch, m=quad*4+r -> tok
          *(s16x4*)(v_s + (t * 16 + ln15) * 72 + mt * 16 + quad * 4) =
              pack4(acc[0], acc[1], acc[2], acc[3]);
        }
      }
    }
  }
  __syncthreads();

  // ---- phase 2: S^T = K.Q^T (per head), softmax per-lane column -> P^T ----
  // Wave -> (hloc = w>>1, query-tile pair = w&1). Lane ln15 = one query.
  {
    const int hloc  = wave >> 1;
    const int qpair = wave & 1;
    const int var   = ((wh == 15) ? 2 : 0) | ((ww == 15) ? 1 : 0);
    const float* bg = bias_g + var * 4096;
    const float scale = 0.17677669529663687f;   // 32^-0.5
    unsigned short* Pt_h = Pt_s + hloc * 64 * 72;

    s16x8 kf[4];
#pragma unroll
    for (int mtk = 0; mtk < 4; ++mtk)
      kf[mtk] = *(const s16x8*)(k_s + (mtk * 16 + ln15) * 72 + hloc * 32 + quad * 8);

#pragma unroll
    for (int iq = 0; iq < 2; ++iq) {
      int ntq = qpair * 2 + iq;
      int tq  = ntq * 16 + ln15;                 // this lane's query token
      s16x8 qf = *(const s16x8*)(q_s + tq * 72 + hloc * 32 + quad * 8);
      f32x4 acc[4];
#pragma unroll
      for (int mtk = 0; mtk < 4; ++mtk) {
        f32x4 z = {0.f, 0.f, 0.f, 0.f};
        acc[mtk] = mfma16(kf[mtk], qf, z);       // D[tok_k][tok_q]
      }
      float e[4][4];
      float s = 0.f;
#pragma unroll
      for (int mtk = 0; mtk < 4; ++mtk) {
        float4 bb = *(const float4*)(bg + tq * 64 + mtk * 16 + quad * 4);
        float eb[4] = {bb.x, bb.y, bb.z, bb.w};
#pragma unroll
        for (int r = 0; r < 4; ++r) {
          float ev = __expf(acc[mtk][r] * scale + eb[r]);   // |S|<~0.5: safe
          e[mtk][r] = ev;
          s += ev;
        }
      }
      s += __shfl_xor(s, 16);
      s += __shfl_xor(s, 32);
      float rcp = 1.0f / s;
#pragma unroll
      for (int mtk = 0; mtk < 4; ++mtk)
        *(s16x4*)(Pt_h + tq * 72 + mtk * 16 + quad * 4) =
            pack4(e[mtk][0] * rcp, e[mtk][1] * rcp, e[mtk][2] * rcp, e[mtk][3] * rcp);
    }
  }
  __syncthreads();

  // ---- phase 3: O^T = (V^T)(P^T) -> packed ushort4 direct to global ------
  // Wave -> (hloc = w>>1, ch-tile = w&1). oa layout per block: [tok][ch 0..63].
  {
    const int hloc = wave >> 1;
    const int mv   = wave & 1;
    const int ch   = hloc * 32 + mv * 16 + ln15;
    s16x8 vf[2];
#pragma unroll
    for (int ks = 0; ks < 2; ++ks)
      vf[ks] = *(const s16x8*)(v_s + ch * 72 + ks * 32 + quad * 8);
    const unsigned short* Pt_h = Pt_s + hloc * 64 * 72;
    unsigned short* ob = oa_ws + (size_t)bid * 4096;
    const int ch0 = hloc * 32 + mv * 16 + quad * 4;
#pragma unroll
    for (int ntq = 0; ntq < 4; ++ntq) {
      f32x4 acc = {0.f, 0.f, 0.f, 0.f};
#pragma unroll
      for (int ks = 0; ks < 2; ++ks) {
        s16x8 pf = *(const s16x8*)(Pt_h + (ntq * 16 + ln15) * 72 + ks * 32 + quad * 8);
        acc = mfma16(vf[ks], pf, acc);
      }
      int tq = ntq * 16 + ln15;
      *(s16x4*)(ob + tq * 64 + ch0) = pack4(acc[0], acc[1], acc[2], acc[3]);
    }
  }
}

// ---------------- K2: out projection, LDS-free, transposed orientation ------
// D = (Wout^T)(oa^T) = [ch_out][tok]; B-frags straight from global oa
// (16KB/window, L1-resident). float4 stores with rolled-back scatter.
__global__ __launch_bounds__(256, 6)
void swin_proj(const unsigned short* __restrict__ oa_ws,
               const unsigned short* __restrict__ woutT,
               const float* __restrict__ b_out,
               float* __restrict__ out) {
  const int tid  = threadIdx.x;
  const int lane = tid & 63;
  const int wave = tid >> 6;
  const int ln15 = lane & 15;
  const int quad = lane >> 4;

  const int bid = blockIdx.x;            // 16*256
  const int b   = bid >> 8;
  const int win = bid & 255;
  const int wh  = win >> 4, ww = win & 15;

  const unsigned short* oa0 = oa_ws + (size_t)(b * 512 + win * 2) * 4096;

#pragma unroll
  for (int mi = 0; mi < 2; ++mi) {
    int mtile = wave * 2 + mi;                  // 8 ch_out tiles
    const unsigned short* wp = woutT + (mtile * 16 + ln15) * 128 + quad * 8;
    s16x8 af[4];
#pragma unroll
    for (int ks = 0; ks < 4; ++ks) af[ks] = *(const s16x8*)(wp + ks * 32);
    int ch0 = mtile * 16 + quad * 4;
    float4 bo = *(const float4*)(b_out + ch0);
#pragma unroll
    for (int ntq = 0; ntq < 4; ++ntq) {
      f32x4 acc = {0.f, 0.f, 0.f, 0.f};
#pragma unroll
      for (int ks = 0; ks < 4; ++ks) {
        // ch_in = ks*32 + quad*8 (+j): hp = ks>>1, local = (ks&1)*32 + quad*8
        s16x8 bf = *(const s16x8*)(oa0 + (ks >> 1) * 4096 +
                                   (ntq * 16 + ln15) * 64 + (ks & 1) * 32 + quad * 8);
        acc = mfma16(af[ks], bf, acc);
      }
      int tok = ntq * 16 + ln15;
      int ti = tok >> 3, tj = tok & 7;
      int gi = (wh * 8 + ti + 4) & 127;
      int gj = (ww * 8 + tj + 4) & 127;
      float4 st = {acc[0] + bo.x, acc[1] + bo.y, acc[2] + bo.z, acc[3] + bo.w};
      *(float4*)(out + ((b * 128 + gi) * 128 + gj) * 128 + ch0) = st;
    }
  }
}

extern "C" void kernel_launch(void* const* d_in, const int* in_sizes, int n_in,
                              void* d_out, int out_size, void* d_ws, size_t ws_size,
                              hipStream_t stream) {
  const float* x    = (const float*)d_in[0];
  const float* wqkv = (const float*)d_in[1];
  const float* wout = (const float*)d_in[2];
  const float* bout = (const float*)d_in[3];
  const float* pe   = (const float*)d_in[4];
  const float* ulm  = (const float*)d_in[5];
  const float* lrm  = (const float*)d_in[6];

  unsigned short* wqkvT = (unsigned short*)d_ws;              // 384*128
  unsigned short* woutT = wqkvT + 49152;                      // 128*128
  float*          bias_g = (float*)(woutT + 16384);           // 4*64*64 f32
  unsigned short* oa_ws  = (unsigned short*)(bias_g + 16384); // 16*512*4096 bf16 (64MB)

  prep<<<320, 256, 0, stream>>>(wqkv, wout, pe, ulm, lrm, wqkvT, woutT, bias_g);
  swin_attn<<<16 * 256 * 2, 256, 0, stream>>>(x, wqkvT, bias_g, oa_ws);
  swin_proj<<<16 * 256, 256, 0, stream>>>(oa_ws, woutT, bout, (float*)d_out);
}